// Round 5
// baseline (486.064 us; speedup 1.0000x reference)
//
#include <hip/hip_runtime.h>

// VQ-VAE vector quantizer, MI355X.
// pass1: pure fp16-MFMA GEMM emitting only per-64-code chunk maxima (branchless epilogue).
// stageB: per-point cutoff + chunk selection. stageC: rescan selected chunks (~1.02/pt),
// decide clear winners, ballot-collect near-tie candidates. npexact: bitwise numpy
// emulation for near-ties (validated rounds 3-4).
typedef _Float16 half_t;
typedef _Float16 half8 __attribute__((ext_vector_type(8)));
typedef float f32x4 __attribute__((ext_vector_type(4)));
typedef unsigned long long ull;

#define K_CODES 8192
#define D_DIM   256
#define N_PTS   32768
#define HW      1024
#define CHW     262144
#define B_      32
#define W_      32

#define OFF_IDX  8388608
#define OFF_LOSS 8421376

#define KSPLIT 4
#define KRANGE 2048       // codes per by-split
#define NCHUNK 32         // 64-code chunks per split
#define W_WIN  1.5e-4f    // score-space near-tie window (validated r4)
#define WX_SEL 0.63f      // x-space chunk cutoff: W_WIN*8192/2 = 0.6144 + slack

// ws layout (bytes)
#define WS_E16  0x000000u // fp16 emb*8192, row-swizzled, 4MB
#define WS_E2   0x400000u // f32[K] numpy-exact
#define WS_Z2   0x408000u // f32[N] numpy-exact
#define WS_FLAG 0x428000u // count + list
#define WS_SEL8 0x450000u // u64[N] packed chunk ids
#define WS_SCNT 0x490000u // u32[N]
#define WS_PART 0x4B0000u // loss partials
// d_out overlays (bytes; all dead before their region is rewritten):
#define DO_CMAX 0u          // f32[128][N] = 16MB   (pass1 -> stageB)
#define DO_Z16  0x1000000u  // half[N][256] = 16MB  (pass1 -> stageC)
#define DO_CAND 0u          // u32[N*16] = 2MB      (stageC -> npexact; cmax dead)
#define DO_CCNT 0x200000u   // u32[N]

__device__ __forceinline__ unsigned int mono_enc(float f) {
    unsigned int u = __float_as_uint(f);
    return (u & 0x80000000u) ? ~u : (u | 0x80000000u);
}
__device__ __forceinline__ float mono_dec(unsigned int m) {
    unsigned int u = (m & 0x80000000u) ? (m ^ 0x80000000u) : ~m;
    return __uint_as_float(u);
}
__device__ __forceinline__ void glds16(const void* g, void* l) {
    __builtin_amdgcn_global_load_lds(
        (const __attribute__((address_space(1))) unsigned int*)g,
        (__attribute__((address_space(3))) unsigned int*)l, 16, 0, 0);
}

// ---- numpy-exact helpers (validated) ----
__device__ __forceinline__ float np_half128_sq(const float* p, int stride) {
    float r[8];
    #pragma unroll
    for (int j = 0; j < 8; j++) { float v = p[(size_t)j * stride]; r[j] = __fmul_rn(v, v); }
    for (int i = 8; i < 128; i += 8) {
        #pragma unroll
        for (int j = 0; j < 8; j++) {
            float v = p[(size_t)(i + j) * stride];
            r[j] = __fadd_rn(r[j], __fmul_rn(v, v));
        }
    }
    return __fadd_rn(__fadd_rn(__fadd_rn(r[0], r[1]), __fadd_rn(r[2], r[3])),
                     __fadd_rn(__fadd_rn(r[4], r[5]), __fadd_rn(r[6], r[7])));
}
__device__ __forceinline__ float np_sum256_sq(const float* p, int stride) {
    return __fadd_rn(np_half128_sq(p, stride), np_half128_sq(p + (size_t)128 * stride, stride));
}

__global__ void e2np_kernel(const float* __restrict__ emb, float* __restrict__ e2,
                            int* __restrict__ flags) {
    if (blockIdx.x == 0 && threadIdx.x == 0) flags[0] = 0;
    int k = blockIdx.x * blockDim.x + threadIdx.x;
    if (k < K_CODES) e2[k] = np_sum256_sq(emb + (size_t)k * D_DIM, 1);
}

__global__ void z2np_kernel(const float* __restrict__ z, float* __restrict__ z2) {
    int n = blockIdx.x * blockDim.x + threadIdx.x;
    if (n < N_PTS) z2[n] = np_sum256_sq(z + (size_t)(n >> 10) * CHW + (n & (HW - 1)), HW);
}

// emb -> fp16 scaled 2^13 (exact), row-internally XOR-swizzled: slot s at s^(k&7)
__global__ void e16cvt_kernel(const float* __restrict__ emb, uint4* __restrict__ e16) {
    const int k = blockIdx.x * blockDim.x + threadIdx.x;
    if (k >= K_CODES) return;
    const float* src = emb + (size_t)k * D_DIM;
    uint4* dst = e16 + (size_t)k * 32;
    #pragma unroll
    for (int s = 0; s < 32; s++) {
        union { half_t h[8]; uint4 u; } t;
        #pragma unroll
        for (int j = 0; j < 8; j++) t.h[j] = (half_t)(src[s * 8 + j] * 8192.0f);
        dst[s ^ (k & 7)] = t.u;
    }
}

// Pass-1: dense fp16 MFMA GEMM; epilogue = per-64-code chunk max only (no indices).
__global__ __launch_bounds__(256, 2) void pass1_kernel(
        const float* __restrict__ z, const uint4* __restrict__ e16,
        float* __restrict__ cmax, half_t* __restrict__ z16) {
    __shared__ __align__(16) char sA[65536];   // 2 x 32KB code-tile double buffer
    const int tid  = threadIdx.x;
    const int lane = tid & 63;
    const int wave = tid >> 6;
    const int col  = lane & 15;
    const int quad = lane >> 4;
    const int bx = blockIdx.x, by = blockIdx.y;
    const int p0 = bx * 256;
    const int bb = bx >> 2;
    const int hwb = (bx & 3) * 256 + wave * 64;
    const int kbase = by * KRANGE;

    // B-fragments: 64 points x D=256 in fp16 registers
    half8 zb[4][8];
    #pragma unroll
    for (int n = 0; n < 4; n++) {
        const int hw = hwb + n * 16 + col;
        const float* zp = z + (size_t)bb * CHW + hw;
        #pragma unroll
        for (int ks = 0; ks < 8; ks++) {
            const int d0 = ks * 32 + quad * 8;
            union { half_t h[8]; half8 v; } u;
            #pragma unroll
            for (int j = 0; j < 8; j++) u.h[j] = (half_t)zp[(size_t)(d0 + j) * HW];
            zb[n][ks] = u.v;
        }
    }
    // side-output: packed fp16 z rows for stageC (once, by==0)
    if (by == 0) {
        #pragma unroll
        for (int n = 0; n < 4; n++) {
            half_t* dst = z16 + (size_t)(p0 + wave * 64 + n * 16 + col) * 256 + quad * 8;
            #pragma unroll
            for (int ks = 0; ks < 8; ks++) *(half8*)(dst + ks * 32) = zb[n][ks];
        }
    }

    const char* esrc = (const char*)e16 + (size_t)kbase * 512;
    {   // prologue: stage chunk 0 -> buf 0
        const char* s0 = esrc + wave * 1024 + lane * 16;
        char* d0 = sA + wave * 1024;
        #pragma unroll
        for (int i = 0; i < 8; i++) glds16(s0 + i * 4096, d0 + i * 4096);
    }
    __syncthreads();

    int cur = 0;
    for (int c = 0; c < NCHUNK; ++c) {
        if (c + 1 < NCHUNK) {
            const char* s0 = esrc + (size_t)(c + 1) * 32768 + wave * 1024 + lane * 16;
            char* d0 = sA + (cur ^ 1) * 32768 + wave * 1024;
            #pragma unroll
            for (int i = 0; i < 8; i++) glds16(s0 + i * 4096, d0 + i * 4096);
        }
        f32x4 acc[4][4];
        #pragma unroll
        for (int m = 0; m < 4; m++)
            #pragma unroll
            for (int n = 0; n < 4; n++) acc[m][n] = (f32x4){0.f, 0.f, 0.f, 0.f};

        const char* base = sA + cur * 32768 + col * 512;
        #pragma unroll
        for (int ks = 0; ks < 8; ks++) {
            const int so = ((ks * 4 + quad) ^ (col & 7)) * 16;
            half8 a[4];
            #pragma unroll
            for (int m = 0; m < 4; m++) a[m] = *(const half8*)(base + m * 8192 + so);
            #pragma unroll
            for (int m = 0; m < 4; m++)
                #pragma unroll
                for (int n = 0; n < 4; n++)
                    acc[m][n] = __builtin_amdgcn_mfma_f32_16x16x32_f16(a[m], zb[n][ks], acc[m][n], 0, 0, 0);
        }
        // branchless chunk-max epilogue
        const int sub = by * NCHUNK + c;
        #pragma unroll
        for (int n = 0; n < 4; n++) {
            float xm = acc[0][n][0];
            #pragma unroll
            for (int m = 0; m < 4; m++)
                #pragma unroll
                for (int r = 0; r < 4; r++) xm = fmaxf(xm, acc[m][n][r]);
            xm = fmaxf(xm, __shfl_xor(xm, 16, 64));
            xm = fmaxf(xm, __shfl_xor(xm, 32, 64));
            if (quad == 0)
                cmax[(size_t)sub * N_PTS + p0 + wave * 64 + n * 16 + col] = xm;
        }
        __syncthreads();
        cur ^= 1;
    }
}

// stageB: per-point cutoff + chunk selection
__global__ __launch_bounds__(256) void stageb_kernel(
        const float* __restrict__ cmax, ull* __restrict__ sel8, int* __restrict__ scnt) {
    const int pt = blockIdx.x * 256 + threadIdx.x;
    float xmax = -3.0e38f;
    #pragma unroll 8
    for (int s = 0; s < 128; s++) xmax = fmaxf(xmax, cmax[(size_t)s * N_PTS + pt]);
    const float cut = xmax - WX_SEL;
    ull pack = 0; int cnt = 0;
    for (int s = 0; s < 128; s++) {
        if (cmax[(size_t)s * N_PTS + pt] >= cut) {
            if (cnt < 8) pack |= ((ull)(unsigned)s) << (8 * cnt);
            cnt++;
        }
    }
    sel8[pt] = pack; scnt[pt] = cnt;
}

// fp32 serial dot of fp16 inputs (consistent across stageC passes)
__device__ __forceinline__ float dotx(const uint4* __restrict__ e16,
                                      const float* __restrict__ zr, int code) {
    const uint4* er = e16 + (size_t)code * 32;
    const int c7 = code & 7;
    float x = 0.f;
    #pragma unroll 8
    for (int j = 0; j < 32; j++) {
        uint4 v = er[j ^ c7];
        const half_t* h = (const half_t*)&v;
        #pragma unroll
        for (int q = 0; q < 8; q++) x = fmaf((float)h[q], zr[j * 8 + q], x);
    }
    return x;
}

// stageC: one wave per point; rescan selected chunks, decide/flag, collect candidates
__global__ __launch_bounds__(256) void stagec_kernel(
        const half_t* __restrict__ z16, const uint4* __restrict__ e16,
        const ull* __restrict__ sel8, const int* __restrict__ scnt,
        int* __restrict__ flags, unsigned* __restrict__ cand,
        unsigned* __restrict__ candcnt, float* __restrict__ dout) {
    __shared__ float zrow[4][256];
    const int tid = threadIdx.x, lane = tid & 63, wave = tid >> 6;
    const int gw0 = blockIdx.x * 4 + wave;
    for (int pt = gw0; pt < N_PTS; pt += gridDim.x * 4) {   // uniform 8 iters/wave
        __syncthreads();
        {
            const unsigned short* zp = (const unsigned short*)(z16 + (size_t)pt * 256);
            ushort4 v = *(const ushort4*)(zp + lane * 4);
            const half_t* h = (const half_t*)&v;
            #pragma unroll
            for (int q = 0; q < 4; q++) zrow[wave][lane * 4 + q] = (float)h[q];
        }
        __syncthreads();
        const int cnt = scnt[pt];
        const ull s8 = sel8[pt];
        const bool dense = (cnt > 8);          // ~never
        const int niter = dense ? 128 : cnt;
        ull r1 = ~0ull, r2 = ~0ull;
        for (int it = 0; it < niter; it++) {
            const int sub = dense ? it : (int)((s8 >> (8 * it)) & 0xFFu);
            const int code = sub * 64 + lane;
            const float sc = dotx(e16, zrow[wave], code) * (-2.0f / 8192.0f);
            const ull p = ((ull)mono_enc(sc) << 32) | (unsigned)code;
            if (p < r1) { r2 = r1; r1 = p; } else if (p < r2) r2 = p;
        }
        #pragma unroll
        for (int s = 1; s < 64; s <<= 1) {
            const ull o1 = __shfl_xor(r1, s, 64);
            const ull o2 = __shfl_xor(r2, s, 64);
            if (o1 < r1) { r2 = (r1 < o2) ? r1 : o2; r1 = o1; }
            else         { r2 = (o1 < r2) ? o1 : r2; }
        }
        const float v1 = mono_dec((unsigned)(r1 >> 32));
        const float v2 = mono_dec((unsigned)(r2 >> 32));
        dout[OFF_IDX + pt] = (float)(unsigned)(r1 & 0xFFFFFFFFu);  // provisional/final
        if (v2 - v1 < W_WIN) {
            if (lane == 0) { const int pos = atomicAdd(flags, 1); flags[16 + pos] = pt; }
            const float thr = v1 + W_WIN;
            int base = 0;
            for (int it = 0; it < niter; it++) {
                const int sub = dense ? it : (int)((s8 >> (8 * it)) & 0xFFu);
                const int code = sub * 64 + lane;
                const float sc = dotx(e16, zrow[wave], code) * (-2.0f / 8192.0f);
                const ull m = __ballot(sc < thr);
                const int pos = base + (int)__popcll(m & ((1ull << lane) - 1ull));
                if (sc < thr && pos < 16) cand[pt * 16 + pos] = (unsigned)code;
                base += (int)__popcll(m);
            }
            if (lane == 0) candcnt[pt] = (unsigned)base;
        }
    }
}

// numpy-bitwise re-decision (validated): d = fl(fl(z2+e2) - 2*serialFMA(z,e))
__global__ __launch_bounds__(256) void npexact_kernel(
        const float* __restrict__ z, const float* __restrict__ emb,
        const float* __restrict__ e2, const float* __restrict__ z2,
        const unsigned* __restrict__ cand, const unsigned* __restrict__ candcnt,
        const int* __restrict__ flags, float* __restrict__ dout) {
    const int wave = (blockIdx.x * blockDim.x + threadIdx.x) >> 6;
    const int lane = threadIdx.x & 63;
    const int nw   = (gridDim.x * blockDim.x) >> 6;
    const int count = flags[0];
    for (int f = wave; f < count; f += nw) {
        const int n = flags[16 + f];
        int cc = (int)candcnt[n]; if (cc > 16) cc = 16;
        float d; int k;
        if (lane < cc) {
            k = (int)cand[n * 16 + lane];
            const float* zp = z + (size_t)(n >> 10) * CHW + (n & (HW - 1));
            const float* ep = emb + (size_t)k * D_DIM;
            float m = 0.f;
            for (int c = 0; c < D_DIM; c++) m = fmaf(zp[(size_t)c * HW], ep[c], m);
            d = __fsub_rn(__fadd_rn(z2[n], e2[k]), __fmul_rn(2.0f, m));
        } else { d = 3.0e38f; k = 1 << 20; }
        #pragma unroll
        for (int s = 1; s < 16; s <<= 1) {
            const float od = __shfl_xor(d, s, 64);
            const int   ok = __shfl_xor(k, s, 64);
            if (od < d || (od == d && ok < k)) { d = od; k = ok; }
        }
        if (lane == 0) dout[OFF_IDX + n] = (float)k;
    }
}

// gather emb[idx] -> (B,C,H,W) coalesced via LDS bounce; per-block loss partial
__global__ __launch_bounds__(256) void gather_kernel(
        const float* __restrict__ z, const float* __restrict__ emb,
        float* __restrict__ dout, float* __restrict__ partials) {
    __shared__ __align__(16) float qs[D_DIM][W_ + 1];
    __shared__ float red[4];
    const int bh = blockIdx.x;
    const int b = bh >> 5, h = bh & 31;
    const int tid = threadIdx.x;

    const float* idxf = dout + OFF_IDX + bh * W_;
    const int w  = tid >> 3;
    const int cq = tid & 7;
    const int idx_w = (int)idxf[w];
    const float* erow = emb + (size_t)idx_w * D_DIM;
    #pragma unroll
    for (int it = 0; it < 8; it++) {
        const int c4 = (it * 8 + cq) * 4;
        float4 v = *(const float4*)(erow + c4);
        qs[c4 + 0][w] = v.x; qs[c4 + 1][w] = v.y;
        qs[c4 + 2][w] = v.z; qs[c4 + 3][w] = v.w;
    }
    __syncthreads();

    const int w2 = tid & 31, cg = tid >> 5;
    float ss = 0.f;
    const float* zbh = z    + (size_t)b * CHW + h * W_;
    float*       obh = dout + (size_t)b * CHW + h * W_;
    #pragma unroll
    for (int it = 0; it < 32; it++) {
        const int c = cg * 32 + it;
        const float q  = qs[c][w2];
        const float zv = zbh[(size_t)c * HW + w2];
        obh[(size_t)c * HW + w2] = q;
        const float dd = q - zv;
        ss = fmaf(dd, dd, ss);
    }
    #pragma unroll
    for (int m = 1; m < 64; m <<= 1) ss += __shfl_xor(ss, m, 64);
    const int lane = tid & 63, wv = tid >> 6;
    if (lane == 0) red[wv] = ss;
    __syncthreads();
    if (tid == 0) partials[bh] = red[0] + red[1] + red[2] + red[3];
}

__global__ void loss_kernel(const float* __restrict__ partials, float* __restrict__ dout) {
    __shared__ float sv[256];
    const int tid = threadIdx.x;
    float s = 0.f;
    #pragma unroll
    for (int i = 0; i < 4; i++) s += partials[tid + 256 * i];
    sv[tid] = s;
    __syncthreads();
    for (int st = 128; st > 0; st >>= 1) {
        if (tid < st) sv[tid] += sv[tid + st];
        __syncthreads();
    }
    if (tid == 0) dout[OFF_LOSS] = sv[0] * (1.25f / 8388608.0f);
}

extern "C" void kernel_launch(void* const* d_in, const int* in_sizes, int n_in,
                              void* d_out, int out_size, void* d_ws, size_t ws_size,
                              hipStream_t stream) {
    const float* z   = (const float*)d_in[0];   // (32,256,32,32)
    const float* emb = (const float*)d_in[1];   // (8192,256)
    float* dout = (float*)d_out;

    char* ws  = (char*)d_ws;
    char* dob = (char*)d_out;
    uint4*  e16   = (uint4*)(ws + WS_E16);
    float*  e2    = (float*)(ws + WS_E2);
    float*  z2    = (float*)(ws + WS_Z2);
    int*    flags = (int*)(ws + WS_FLAG);
    ull*    sel8  = (ull*)(ws + WS_SEL8);
    int*    scnt  = (int*)(ws + WS_SCNT);
    float*  part  = (float*)(ws + WS_PART);
    float*    cmax = (float*)(dob + DO_CMAX);
    half_t*   z16  = (half_t*)(dob + DO_Z16);
    unsigned* cand = (unsigned*)(dob + DO_CAND);
    unsigned* ccnt = (unsigned*)(dob + DO_CCNT);

    hipLaunchKernelGGL(e16cvt_kernel,  dim3(32),          dim3(256), 0, stream, emb, e16);
    hipLaunchKernelGGL(e2np_kernel,    dim3(32),          dim3(256), 0, stream, emb, e2, flags);
    hipLaunchKernelGGL(z2np_kernel,    dim3(128),         dim3(256), 0, stream, z, z2);
    hipLaunchKernelGGL(pass1_kernel,   dim3(128, KSPLIT), dim3(256), 0, stream, z, e16, cmax, z16);
    hipLaunchKernelGGL(stageb_kernel,  dim3(128),         dim3(256), 0, stream, cmax, sel8, scnt);
    hipLaunchKernelGGL(stagec_kernel,  dim3(1024),        dim3(256), 0, stream, z16, e16, sel8, scnt, flags, cand, ccnt, dout);
    hipLaunchKernelGGL(npexact_kernel, dim3(256),         dim3(256), 0, stream, z, emb, e2, z2, cand, ccnt, flags, dout);
    hipLaunchKernelGGL(gather_kernel,  dim3(B_ * 32),     dim3(256), 0, stream, z, emb, dout, part);
    hipLaunchKernelGGL(loss_kernel,    dim3(1),           dim3(256), 0, stream, part, dout);
}